// Round 10
// baseline (147.301 us; speedup 1.0000x reference)
//
#include <hip/hip_runtime.h>
#include <hip/hip_bf16.h>
#include <math.h>

#define EPSV 1e-6f
#define LAMBDAV 1e-3f
#define LN_2PI 1.8378770664093453f

__device__ __forceinline__ float bflo(unsigned int u) {
    union { unsigned int i; float f; } x; x.i = u << 16; return x.f;
}
__device__ __forceinline__ float bfhi(unsigned int u) {
    union { unsigned int i; float f; } x; x.i = u & 0xffff0000u; return x.f;
}

// Kernel 0: gather p_in -> P[n][i2][p] (fp32, 128*288*16 = 2.36 MB).
// grid (288, 4) x 512: thread = (i2, k=tid>>4 -> n, p=tid&15).
__global__ __launch_bounds__(512)
void gather_p_kernel(const float* __restrict__ x, float* __restrict__ P)
{
    const int i2 = blockIdx.x;
    const int k  = threadIdx.x >> 4;
    const int p  = threadIdx.x & 15;
    const int n  = blockIdx.y * 32 + k;

    // reference reshape scramble: g=i2*16+p; k2=g>>9; c2=g&511; f=k2*544+c2=ci*9+kk
    int e  = i2 * 16 + p;
    int k2 = e >> 9, c2 = e & 511;
    int f  = k2 * 544 + c2;
    int ci = f / 9, kk = f - ci * 9;
    int bi = n >> 6, oi = (n >> 3) & 7, oj = n & 7;
    int row = 2 * oi + kk / 3 - 1;
    int col = 2 * oj + (kk - (kk / 3) * 3) - 1;
    float val = 0.f;
    if ((unsigned)row < 16u && (unsigned)col < 16u)
        val = x[((bi * 16 + row) * 16 + col) * 544 + ci];
    P[(size_t)n * 4608 + i2 * 16 + p] = val;
}

// Kernel 1: v[nl, i2, cq] bf16. Thread = one (c,q); 16 w regs. pv comes from P
// via wave-uniform loads (scalar-cache path: no LDS, no per-lane VMEM).
// grid = (288 i2, chunks of 64 positions).
__global__ __launch_bounds__(512)
void conv_v_kernel(const float* __restrict__ P, const float* __restrict__ w,
                   __hip_bfloat16* __restrict__ vout, int n0, int cnt)
{
    const int i2  = blockIdx.x;
    const int kb0 = blockIdx.y * 64;
    const int tid = threadIdx.x;
    const int c1 = tid >> 4, q1 = tid & 15;

    const float* wp = w + (size_t)i2 * 8192 + c1 * 256 + q1;
    float wr[16];
    #pragma unroll
    for (int p = 0; p < 16; ++p) wr[p] = wp[p * 16];

    const int kmax = min(64, cnt - kb0);
    #pragma unroll 4
    for (int k = 0; k < kmax; ++k) {
        // uniform address (blockIdx + loop var only) -> s_load_dwordx4
        const float4* pp = (const float4*)(P + (size_t)(n0 + kb0 + k) * 4608 + i2 * 16);
        const float4 pa = pp[0], pb = pp[1], pc = pp[2], pd = pp[3];
        float acc;
        acc  = pa.x * wr[0]  + pa.y * wr[1]  + pa.z * wr[2]  + pa.w * wr[3];
        acc += pb.x * wr[4]  + pb.y * wr[5]  + pb.z * wr[6]  + pb.w * wr[7];
        acc += pc.x * wr[8]  + pc.y * wr[9]  + pc.z * wr[10] + pc.w * wr[11];
        acc += pd.x * wr[12] + pd.y * wr[13] + pd.z * wr[14] + pd.w * wr[15];
        vout[((size_t)(kb0 + k) * 288 + i2) * 512 + tid] = __float2bfloat16(acc);
    }
}

// Kernel 2: EM routing, fused single sweep, q split across wave halves,
// 2-row ILP (rows 2j,2j+1 per iteration: independent shfl/exp chains).
// Block = 1024 = 16 waves; wave wv owns rows {16k+wv}.
__global__ __launch_bounds__(1024, 4)
void em_routing_kernel(const float* __restrict__ x,
                       const unsigned short* __restrict__ v,   // [n][i][cq] bf16
                       const float* __restrict__ beta_u,
                       const float* __restrict__ beta_a,
                       float* __restrict__ out, int n0)
{
    __shared__ float fct_s[288];            // a/(a+eps)
    __shared__ float red_s[16 * 64 * 17];   // [wave][lane][s0|s1[8]|s2[8]] 69.6 KB
    __shared__ float mu_s[32 * 17];
    __shared__ float i2ss_s[32 * 17];
    __shared__ float hlog_s[32 * 17];
    __shared__ float rsum_s[32];
    __shared__ float aout_s[32];
    __shared__ float kc_s[32];

    const int n   = n0 + blockIdx.x;
    const int tid = threadIdx.x;
    const int bi = n >> 6, oi = (n >> 3) & 7, oj = n & 7;

    if (tid < 288) {
        // a_in gather: c2 in [512,544)
        int k2 = tid >> 5;
        int c2 = 512 + (tid & 31);
        int f  = k2 * 544 + c2;
        int ci = f / 9;
        int kk = f - ci * 9;
        int row = 2 * oi + kk / 3 - 1;
        int col = 2 * oj + (kk - (kk / 3) * 3) - 1;
        float a = 0.f;
        if ((unsigned)row < 16u && (unsigned)col < 16u)
            a = x[((bi * 16 + row) * 16 + col) * 544 + ci];
        fct_s[tid] = a / (a + EPSV);   // sum_c r*a == a -> rr = softmax * fct
    }
    __syncthreads();

    const unsigned short* vb = v + (size_t)blockIdx.x * 288 * 512;
    const int wv   = tid >> 6;      // wave 0..15
    const int lane = tid & 63;
    const int c    = lane & 31;
    const int qh   = lane >> 5;     // q-half 0/1
    const int qb   = qh * 8;

    for (int t = 0; t < 3; ++t) {
        float mu8[8], is8[8], kcv = 0.f;
        if (t > 0) {
            #pragma unroll
            for (int j = 0; j < 8; ++j) {
                mu8[j] = mu_s[c * 17 + qb + j];
                is8[j] = i2ss_s[c * 17 + qb + j];
            }
            kcv = kc_s[c];
        }

        float s0 = 0.f, s1[8], s2[8];
        #pragma unroll
        for (int j = 0; j < 8; ++j) { s1[j] = 0.f; s2[j] = 0.f; }

        for (int kp = 0; kp < 9; ++kp) {
            const int ia = (2 * kp) * 16 + wv;
            const int ib = (2 * kp + 1) * 16 + wv;
            uint4 ua = *(const uint4*)(vb + (size_t)ia * 512 + c * 16 + qb);
            uint4 ub = *(const uint4*)(vb + (size_t)ib * 512 + c * 16 + qb);
            float va[8], vvb[8];
            va[0] = bflo(ua.x); va[1] = bfhi(ua.x);
            va[2] = bflo(ua.y); va[3] = bfhi(ua.y);
            va[4] = bflo(ua.z); va[5] = bfhi(ua.z);
            va[6] = bflo(ua.w); va[7] = bfhi(ua.w);
            vvb[0] = bflo(ub.x); vvb[1] = bfhi(ub.x);
            vvb[2] = bflo(ub.y); vvb[3] = bfhi(ub.y);
            vvb[4] = bflo(ub.z); vvb[5] = bfhi(ub.z);
            vvb[6] = bflo(ub.w); vvb[7] = bfhi(ub.w);

            float rra, rrb;
            if (t == 0) {
                rra = fct_s[ia] * 0.03125f;
                rrb = fct_s[ib] * 0.03125f;
            } else {
                float pa = 0.f, pb = 0.f;
                #pragma unroll
                for (int j = 0; j < 8; ++j) {
                    float da = va[j] - mu8[j];
                    float db = vvb[j] - mu8[j];
                    pa += da * da * is8[j];
                    pb += db * db * is8[j];
                }
                pa += __shfl_xor(pa, 32, 64);
                pb += __shfl_xor(pb, 32, 64);
                float acca = kcv - pa;
                float accb = kcv - pb;
                // two independent width-32 softmax chains
                float mxa = acca, mxb = accb;
                mxa = fmaxf(mxa, __shfl_xor(mxa, 1, 32));  mxb = fmaxf(mxb, __shfl_xor(mxb, 1, 32));
                mxa = fmaxf(mxa, __shfl_xor(mxa, 2, 32));  mxb = fmaxf(mxb, __shfl_xor(mxb, 2, 32));
                mxa = fmaxf(mxa, __shfl_xor(mxa, 4, 32));  mxb = fmaxf(mxb, __shfl_xor(mxb, 4, 32));
                mxa = fmaxf(mxa, __shfl_xor(mxa, 8, 32));  mxb = fmaxf(mxb, __shfl_xor(mxb, 8, 32));
                mxa = fmaxf(mxa, __shfl_xor(mxa, 16, 32)); mxb = fmaxf(mxb, __shfl_xor(mxb, 16, 32));
                float ea = expf(acca - mxa);
                float eb = expf(accb - mxb);
                float sa = ea, sb = eb;
                sa += __shfl_xor(sa, 1, 32);  sb += __shfl_xor(sb, 1, 32);
                sa += __shfl_xor(sa, 2, 32);  sb += __shfl_xor(sb, 2, 32);
                sa += __shfl_xor(sa, 4, 32);  sb += __shfl_xor(sb, 4, 32);
                sa += __shfl_xor(sa, 8, 32);  sb += __shfl_xor(sb, 8, 32);
                sa += __shfl_xor(sa, 16, 32); sb += __shfl_xor(sb, 16, 32);
                rra = (ea / sa) * fct_s[ia];
                rrb = (eb / sb) * fct_s[ib];
            }

            s0 += rra + rrb;
            #pragma unroll
            for (int j = 0; j < 8; ++j) {
                s1[j] += rra * va[j] + rrb * vvb[j];
                s2[j] += rra * va[j] * va[j] + rrb * vvb[j] * vvb[j];
            }
        }

        // per-wave partials -> LDS (stride 17: 2-way bank alias = free)
        {
            float* dst = &red_s[(wv * 64 + lane) * 17];
            dst[0] = s0;
            #pragma unroll
            for (int j = 0; j < 8; ++j) { dst[1 + j] = s1[j]; dst[9 + j] = s2[j]; }
        }
        __syncthreads();

        // final 16-way reduce + mu/sigma (thread = (c2,q2))
        if (tid < 512) {
            int c2 = tid >> 4, q2 = tid & 15;
            int qh2 = q2 >> 3, j2 = q2 & 7;
            float S0 = 0.f, S1 = 0.f, S2 = 0.f;
            #pragma unroll
            for (int wvi = 0; wvi < 16; ++wvi) {
                S0 += red_s[(wvi * 64 + c2) * 17];
                const float* sp = &red_s[(wvi * 64 + qh2 * 32 + c2) * 17];
                S1 += sp[1 + j2];
                S2 += sp[9 + j2];
            }
            if (q2 == 0) rsum_s[c2] = S0;
            float invr = 1.0f / (S0 + EPSV);
            float w0  = S0 * invr;
            float m   = S1 * invr;
            float s2p = S2 * invr;
            float sig = s2p - m * m * (2.0f - w0);   // == sum coeff*(v-mu)^2
            sig = fmaxf(sig + EPSV, 1e-4f);
            float hl = 0.5f * logf(sig);
            mu_s[c2 * 17 + q2]   = m;
            hlog_s[c2 * 17 + q2] = hl;
            i2ss_s[c2 * 17 + q2] = 1.0f / (2.0f * sig);
        }
        __syncthreads();

        // a_out + per-c ln_p constant
        if (tid < 32) {
            float cs = 0.f, shl = 0.f;
            float bu = beta_u[tid];
            #pragma unroll
            for (int q = 0; q < 16; ++q) { float hl = hlog_s[tid * 17 + q]; shl += hl; cs += bu + hl; }
            cs *= rsum_s[tid];
            float arg = LAMBDAV * (beta_a[tid] - cs);
            float ao  = 1.0f / (1.0f + expf(-arg));
            ao = fminf(fmaxf(ao, 1e-4f), 1.0f - 1e-4f);
            aout_s[tid] = ao;
            kc_s[tid]   = logf(ao + EPSV) - shl - 8.0f * LN_2PI;
        }
        __syncthreads();
    }

    // epilogue (fp32): p_out [0,65536) | a_out [65536,69632) | out [69632,139264)
    if (tid < 512) {
        int c2 = tid >> 4, q2 = tid & 15;
        float mu = mu_s[c2 * 17 + q2];
        if (isnan(mu)) mu = 0.f;
        mu = fminf(fmaxf(mu, -10000.f), 10000.f);
        out[(size_t)n * 512 + tid] = mu;
        out[69632 + (size_t)n * 544 + tid] = mu;
        if (tid < 32) {
            float ao = aout_s[tid];
            if (isnan(ao)) ao = 0.5f;
            out[65536 + n * 32 + tid] = ao;
            out[69632 + n * 544 + 512 + tid] = ao;
        }
    }
}

extern "C" void kernel_launch(void* const* d_in, const int* in_sizes, int n_in,
                              void* d_out, int out_size, void* d_ws, size_t ws_size,
                              hipStream_t stream) {
    const float* x  = (const float*)d_in[0];
    const float* w  = (const float*)d_in[1];
    const float* bu = (const float*)d_in[2];
    const float* ba = (const float*)d_in[3];
    float* out = (float*)d_out;

    // ws layout: P (128*4608 fp32 = 2.36 MB) | v (CN*288*512 bf16)
    float* P = (float*)d_ws;
    const size_t p_bytes = (size_t)128 * 4608 * sizeof(float);
    __hip_bfloat16* v = (__hip_bfloat16*)((char*)d_ws + p_bytes);

    const size_t per_n = (size_t)288 * 512 * sizeof(__hip_bfloat16); // 294912 B
    long avail = (long)ws_size - (long)p_bytes;
    int CN = (avail > 0) ? (int)(avail / per_n) : 1;
    if (CN < 1)   CN = 1;
    if (CN > 128) CN = 128;

    gather_p_kernel<<<dim3(288, 4), dim3(512), 0, stream>>>(x, P);

    for (int ncur = 0; ncur < 128; ncur += CN) {
        int cnt = (128 - ncur < CN) ? (128 - ncur) : CN;
        conv_v_kernel<<<dim3(288, (cnt + 63) / 64), dim3(512), 0, stream>>>(
            P, w, v, ncur, cnt);
        em_routing_kernel<<<dim3(cnt), dim3(1024), 0, stream>>>(
            x, (const unsigned short*)v, bu, ba, out, ncur);
    }
}

// Round 11
// 140.906 us; speedup vs baseline: 1.0454x; 1.0454x over previous
//
#include <hip/hip_runtime.h>
#include <hip/hip_bf16.h>
#include <math.h>

#define EPSV 1e-6f
#define LAMBDAV 1e-3f
#define LN_2PI 1.8378770664093453f

__device__ __forceinline__ float bflo(unsigned int u) {
    union { unsigned int i; float f; } x; x.i = u << 16; return x.f;
}
__device__ __forceinline__ float bfhi(unsigned int u) {
    union { unsigned int i; float f; } x; x.i = u & 0xffff0000u; return x.f;
}
__device__ __forceinline__ unsigned short f2bf(float f) {
    __hip_bfloat16 h = __float2bfloat16(f);
    return *(unsigned short*)&h;
}

typedef __attribute__((ext_vector_type(8))) short s8v;
typedef __attribute__((ext_vector_type(4))) float f4v;

// Kernel 0: gather p_in -> Pb[n][i2*16+p] (bf16, 128*4608 = 1.18 MB).
__global__ __launch_bounds__(512)
void gather_p_kernel(const float* __restrict__ x, unsigned short* __restrict__ Pb)
{
    const int i2 = blockIdx.x;
    const int k  = threadIdx.x >> 4;
    const int p  = threadIdx.x & 15;
    const int n  = blockIdx.y * 32 + k;

    // reference reshape scramble: g=i2*16+p; k2=g>>9; c2=g&511; f=k2*544+c2=ci*9+kk
    int e  = i2 * 16 + p;
    int k2 = e >> 9, c2 = e & 511;
    int f  = k2 * 544 + c2;
    int ci = f / 9, kk = f - ci * 9;
    int bi = n >> 6, oi = (n >> 3) & 7, oj = n & 7;
    int row = 2 * oi + kk / 3 - 1;
    int col = 2 * oj + (kk - (kk / 3) * 3) - 1;
    float val = 0.f;
    if ((unsigned)row < 16u && (unsigned)col < 16u)
        val = x[((bi * 16 + row) * 16 + col) * 544 + ci];
    Pb[(size_t)n * 4608 + i2 * 16 + p] = f2bf(val);
}

// Kernel 1: MFMA conv. One block (256 thr, 4 waves) per i2 handles the full
// M=512(cq) x N=128(n) x K=16(p) GEMM as 256 mfma_f32_16x16x32_bf16 (K padded
// to 32 with zeros). Verified layouts: A[m=lane&15][k=quad*8+j],
// B[k=quad*8+j][n=lane&15], D col=lane&15 row=quad*4+reg.
__global__ __launch_bounds__(256)
void conv_v_kernel(const unsigned short* __restrict__ Pb, const float* __restrict__ w,
                   __hip_bfloat16* __restrict__ vout, int n0, int cnt)
{
    __shared__ unsigned short wb[512 * 40];  // [cq][p pad 40] 40 KB (16B-aligned rows, 2-way banks)
    __shared__ unsigned short pb[128 * 40];  // [n][p pad 40] 10 KB

    const int i2  = blockIdx.x;
    const int tid = threadIdx.x;

    // zero k=16..31 padding (mfma reads k<32; 32..39 never read)
    for (int u = tid; u < 512 * 8; u += 256) {
        int r = u >> 3, j = u & 7;
        *(unsigned int*)&wb[r * 40 + 16 + j * 2] = 0;
    }
    for (int u = tid; u < 128 * 8; u += 256) {
        int r = u >> 3, j = u & 7;
        *(unsigned int*)&pb[r * 40 + 16 + j * 2] = 0;
    }
    // stage w[i2][c][p][q] fp32 -> wb[c*16+q][p] bf16
    #pragma unroll 4
    for (int u = 0; u < 32; ++u) {
        int idx = u * 256 + tid;               // c*256 + p*16 + q
        int c = idx >> 8, p = (idx >> 4) & 15, q = idx & 15;
        wb[(c * 16 + q) * 40 + p] = f2bf(w[(size_t)i2 * 8192 + idx]);
    }
    // stage Pb[n0+nn][i2*16+p] -> pb[nn][p]
    #pragma unroll
    for (int u = 0; u < 8; ++u) {
        int idx = u * 256 + tid;               // nn*16 + p
        int nn = idx >> 4, p = idx & 15;
        unsigned short val = 0;
        if (nn < cnt) val = Pb[(size_t)(n0 + nn) * 4608 + i2 * 16 + p];
        pb[nn * 40 + p] = val;
    }
    __syncthreads();

    const int lane = tid & 63;
    const int wv   = tid >> 6;
    const int l16  = lane & 15;
    const int quad = lane >> 4;
    const int cq0  = wv * 128;

    s8v afrag[8], bfrag[8];
    #pragma unroll
    for (int mt = 0; mt < 8; ++mt)
        afrag[mt] = *(const s8v*)&wb[(cq0 + mt * 16 + l16) * 40 + quad * 8];
    #pragma unroll
    for (int nt = 0; nt < 8; ++nt)
        bfrag[nt] = *(const s8v*)&pb[(nt * 16 + l16) * 40 + quad * 8];

    #pragma unroll
    for (int nt = 0; nt < 8; ++nt) {
        const int nl = nt * 16 + l16;          // local n
        const bool ok = nl < cnt;
        #pragma unroll
        for (int mt = 0; mt < 8; ++mt) {
            f4v acc = {0.f, 0.f, 0.f, 0.f};
            acc = __builtin_amdgcn_mfma_f32_16x16x32_bf16(afrag[mt], bfrag[nt], acc, 0, 0, 0);
            if (ok) {
                int cq = cq0 + mt * 16 + quad * 4;
                unsigned int lo = f2bf(acc[0]) | ((unsigned int)f2bf(acc[1]) << 16);
                unsigned int hi = f2bf(acc[2]) | ((unsigned int)f2bf(acc[3]) << 16);
                uint2 pk; pk.x = lo; pk.y = hi;
                *(uint2*)((unsigned short*)vout + ((size_t)nl * 288 + i2) * 512 + cq) = pk;
            }
        }
    }
}

// Kernel 2: EM routing, fused single sweep, q split across wave halves,
// 2-row ILP. Block = 1024 = 16 waves; wave wv owns rows {16k+wv}.
__global__ __launch_bounds__(1024, 4)
void em_routing_kernel(const float* __restrict__ x,
                       const unsigned short* __restrict__ v,   // [n][i][cq] bf16
                       const float* __restrict__ beta_u,
                       const float* __restrict__ beta_a,
                       float* __restrict__ out, int n0)
{
    __shared__ float fct_s[288];            // a/(a+eps)
    __shared__ float red_s[16 * 64 * 17];   // [wave][lane][s0|s1[8]|s2[8]] 69.6 KB
    __shared__ float mu_s[32 * 17];
    __shared__ float i2ss_s[32 * 17];
    __shared__ float hlog_s[32 * 17];
    __shared__ float rsum_s[32];
    __shared__ float aout_s[32];
    __shared__ float kc_s[32];

    const int n   = n0 + blockIdx.x;
    const int tid = threadIdx.x;
    const int bi = n >> 6, oi = (n >> 3) & 7, oj = n & 7;

    if (tid < 288) {
        // a_in gather: c2 in [512,544)
        int k2 = tid >> 5;
        int c2 = 512 + (tid & 31);
        int f  = k2 * 544 + c2;
        int ci = f / 9;
        int kk = f - ci * 9;
        int row = 2 * oi + kk / 3 - 1;
        int col = 2 * oj + (kk - (kk / 3) * 3) - 1;
        float a = 0.f;
        if ((unsigned)row < 16u && (unsigned)col < 16u)
            a = x[((bi * 16 + row) * 16 + col) * 544 + ci];
        fct_s[tid] = a / (a + EPSV);   // sum_c r*a == a -> rr = softmax * fct
    }
    __syncthreads();

    const unsigned short* vb = v + (size_t)blockIdx.x * 288 * 512;
    const int wv   = tid >> 6;      // wave 0..15
    const int lane = tid & 63;
    const int c    = lane & 31;
    const int qh   = lane >> 5;     // q-half 0/1
    const int qb   = qh * 8;

    for (int t = 0; t < 3; ++t) {
        float mu8[8], is8[8], kcv = 0.f;
        if (t > 0) {
            #pragma unroll
            for (int j = 0; j < 8; ++j) {
                mu8[j] = mu_s[c * 17 + qb + j];
                is8[j] = i2ss_s[c * 17 + qb + j];
            }
            kcv = kc_s[c];
        }

        float s0 = 0.f, s1[8], s2[8];
        #pragma unroll
        for (int j = 0; j < 8; ++j) { s1[j] = 0.f; s2[j] = 0.f; }

        for (int kp = 0; kp < 9; ++kp) {
            const int ia = (2 * kp) * 16 + wv;
            const int ib = (2 * kp + 1) * 16 + wv;
            uint4 ua = *(const uint4*)(vb + (size_t)ia * 512 + c * 16 + qb);
            uint4 ub = *(const uint4*)(vb + (size_t)ib * 512 + c * 16 + qb);
            float va[8], vvb[8];
            va[0] = bflo(ua.x); va[1] = bfhi(ua.x);
            va[2] = bflo(ua.y); va[3] = bfhi(ua.y);
            va[4] = bflo(ua.z); va[5] = bfhi(ua.z);
            va[6] = bflo(ua.w); va[7] = bfhi(ua.w);
            vvb[0] = bflo(ub.x); vvb[1] = bfhi(ub.x);
            vvb[2] = bflo(ub.y); vvb[3] = bfhi(ub.y);
            vvb[4] = bflo(ub.z); vvb[5] = bfhi(ub.z);
            vvb[6] = bflo(ub.w); vvb[7] = bfhi(ub.w);

            float rra, rrb;
            if (t == 0) {
                rra = fct_s[ia] * 0.03125f;
                rrb = fct_s[ib] * 0.03125f;
            } else {
                float pa = 0.f, pb2 = 0.f;
                #pragma unroll
                for (int j = 0; j < 8; ++j) {
                    float da = va[j] - mu8[j];
                    float db = vvb[j] - mu8[j];
                    pa  += da * da * is8[j];
                    pb2 += db * db * is8[j];
                }
                pa  += __shfl_xor(pa, 32, 64);
                pb2 += __shfl_xor(pb2, 32, 64);
                float acca = kcv - pa;
                float accb = kcv - pb2;
                float mxa = acca, mxb = accb;
                mxa = fmaxf(mxa, __shfl_xor(mxa, 1, 32));  mxb = fmaxf(mxb, __shfl_xor(mxb, 1, 32));
                mxa = fmaxf(mxa, __shfl_xor(mxa, 2, 32));  mxb = fmaxf(mxb, __shfl_xor(mxb, 2, 32));
                mxa = fmaxf(mxa, __shfl_xor(mxa, 4, 32));  mxb = fmaxf(mxb, __shfl_xor(mxb, 4, 32));
                mxa = fmaxf(mxa, __shfl_xor(mxa, 8, 32));  mxb = fmaxf(mxb, __shfl_xor(mxb, 8, 32));
                mxa = fmaxf(mxa, __shfl_xor(mxa, 16, 32)); mxb = fmaxf(mxb, __shfl_xor(mxb, 16, 32));
                float ea = __expf(acca - mxa);
                float eb = __expf(accb - mxb);
                float sa = ea, sb = eb;
                sa += __shfl_xor(sa, 1, 32);  sb += __shfl_xor(sb, 1, 32);
                sa += __shfl_xor(sa, 2, 32);  sb += __shfl_xor(sb, 2, 32);
                sa += __shfl_xor(sa, 4, 32);  sb += __shfl_xor(sb, 4, 32);
                sa += __shfl_xor(sa, 8, 32);  sb += __shfl_xor(sb, 8, 32);
                sa += __shfl_xor(sa, 16, 32); sb += __shfl_xor(sb, 16, 32);
                rra = (ea / sa) * fct_s[ia];
                rrb = (eb / sb) * fct_s[ib];
            }

            s0 += rra + rrb;
            #pragma unroll
            for (int j = 0; j < 8; ++j) {
                s1[j] += rra * va[j] + rrb * vvb[j];
                s2[j] += rra * va[j] * va[j] + rrb * vvb[j] * vvb[j];
            }
        }

        // per-wave partials -> LDS (stride 17: 2-way bank alias = free)
        {
            float* dst = &red_s[(wv * 64 + lane) * 17];
            dst[0] = s0;
            #pragma unroll
            for (int j = 0; j < 8; ++j) { dst[1 + j] = s1[j]; dst[9 + j] = s2[j]; }
        }
        __syncthreads();

        // final 16-way reduce + mu/sigma (thread = (c2,q2))
        if (tid < 512) {
            int c2 = tid >> 4, q2 = tid & 15;
            int qh2 = q2 >> 3, j2 = q2 & 7;
            float S0 = 0.f, S1 = 0.f, S2 = 0.f;
            #pragma unroll
            for (int wvi = 0; wvi < 16; ++wvi) {
                S0 += red_s[(wvi * 64 + c2) * 17];
                const float* sp = &red_s[(wvi * 64 + qh2 * 32 + c2) * 17];
                S1 += sp[1 + j2];
                S2 += sp[9 + j2];
            }
            if (q2 == 0) rsum_s[c2] = S0;
            float invr = 1.0f / (S0 + EPSV);
            float w0  = S0 * invr;
            float m   = S1 * invr;
            float s2p = S2 * invr;
            float sig = s2p - m * m * (2.0f - w0);   // == sum coeff*(v-mu)^2
            sig = fmaxf(sig + EPSV, 1e-4f);
            float hl = 0.5f * logf(sig);
            mu_s[c2 * 17 + q2]   = m;
            hlog_s[c2 * 17 + q2] = hl;
            i2ss_s[c2 * 17 + q2] = 1.0f / (2.0f * sig);
        }
        __syncthreads();

        // a_out + per-c ln_p constant
        if (tid < 32) {
            float cs = 0.f, shl = 0.f;
            float bu = beta_u[tid];
            #pragma unroll
            for (int q = 0; q < 16; ++q) { float hl = hlog_s[tid * 17 + q]; shl += hl; cs += bu + hl; }
            cs *= rsum_s[tid];
            float arg = LAMBDAV * (beta_a[tid] - cs);
            float ao  = 1.0f / (1.0f + expf(-arg));
            ao = fminf(fmaxf(ao, 1e-4f), 1.0f - 1e-4f);
            aout_s[tid] = ao;
            kc_s[tid]   = logf(ao + EPSV) - shl - 8.0f * LN_2PI;
        }
        __syncthreads();
    }

    // epilogue (fp32): p_out [0,65536) | a_out [65536,69632) | out [69632,139264)
    if (tid < 512) {
        int c2 = tid >> 4, q2 = tid & 15;
        float mu = mu_s[c2 * 17 + q2];
        if (isnan(mu)) mu = 0.f;
        mu = fminf(fmaxf(mu, -10000.f), 10000.f);
        out[(size_t)n * 512 + tid] = mu;
        out[69632 + (size_t)n * 544 + tid] = mu;
        if (tid < 32) {
            float ao = aout_s[tid];
            if (isnan(ao)) ao = 0.5f;
            out[65536 + n * 32 + tid] = ao;
            out[69632 + n * 544 + 512 + tid] = ao;
        }
    }
}

extern "C" void kernel_launch(void* const* d_in, const int* in_sizes, int n_in,
                              void* d_out, int out_size, void* d_ws, size_t ws_size,
                              hipStream_t stream) {
    const float* x  = (const float*)d_in[0];
    const float* w  = (const float*)d_in[1];
    const float* bu = (const float*)d_in[2];
    const float* ba = (const float*)d_in[3];
    float* out = (float*)d_out;

    // ws layout: Pb (128*4608 bf16 = 1.18 MB) | v (CN*288*512 bf16)
    unsigned short* Pb = (unsigned short*)d_ws;
    const size_t p_bytes = (size_t)128 * 4608 * sizeof(unsigned short);
    __hip_bfloat16* v = (__hip_bfloat16*)((char*)d_ws + p_bytes);

    const size_t per_n = (size_t)288 * 512 * sizeof(__hip_bfloat16); // 294912 B
    long avail = (long)ws_size - (long)p_bytes;
    int CN = (avail > 0) ? (int)(avail / per_n) : 1;
    if (CN < 1)   CN = 1;
    if (CN > 128) CN = 128;

    gather_p_kernel<<<dim3(288, 4), dim3(512), 0, stream>>>(x, Pb);

    for (int ncur = 0; ncur < 128; ncur += CN) {
        int cnt = (128 - ncur < CN) ? (128 - ncur) : CN;
        conv_v_kernel<<<dim3(288), dim3(256), 0, stream>>>(
            Pb, w, (__hip_bfloat16*)v, ncur, cnt);
        em_routing_kernel<<<dim3(cnt), dim3(1024), 0, stream>>>(
            x, (const unsigned short*)v, bu, ba, out, ncur);
    }
}

// Round 12
// 129.557 us; speedup vs baseline: 1.1370x; 1.0876x over previous
//
#include <hip/hip_runtime.h>
#include <hip/hip_bf16.h>
#include <math.h>

#define EPSV 1e-6f
#define LAMBDAV 1e-3f
#define LN_2PI 1.8378770664093453f

__device__ __forceinline__ float bflo(unsigned int u) {
    union { unsigned int i; float f; } x; x.i = u << 16; return x.f;
}
__device__ __forceinline__ float bfhi(unsigned int u) {
    union { unsigned int i; float f; } x; x.i = u & 0xffff0000u; return x.f;
}
__device__ __forceinline__ unsigned short f2bf(float f) {
    __hip_bfloat16 h = __float2bfloat16(f);
    return *(unsigned short*)&h;
}

typedef __attribute__((ext_vector_type(8))) short s8v;
typedef __attribute__((ext_vector_type(4))) float f4v;

// Kernel 1: MFMA conv with fused patch gather. One block (256 thr) per i2:
// gathers its own 128n x 16p patch slice from x, stages w -> bf16 LDS, runs
// M=512(cq) x N=128(n) x K=16(p) as 256 mfma_f32_16x16x32_bf16.
__global__ __launch_bounds__(256)
void conv_v_kernel(const float* __restrict__ x, const float* __restrict__ w,
                   __hip_bfloat16* __restrict__ vout)
{
    __shared__ unsigned short wb[512 * 40];  // [cq][p pad40]
    __shared__ unsigned short pb[128 * 40];  // [n][p pad40]

    const int i2  = blockIdx.x;
    const int tid = threadIdx.x;

    // zero k=16..31 padding (mfma reads k<32)
    for (int u = tid; u < 512 * 8; u += 256) {
        int r = u >> 3, j = u & 7;
        *(unsigned int*)&wb[r * 40 + 16 + j * 2] = 0;
    }
    for (int u = tid; u < 128 * 8; u += 256) {
        int r = u >> 3, j = u & 7;
        *(unsigned int*)&pb[r * 40 + 16 + j * 2] = 0;
    }
    // stage w[i2][c][p][q] fp32 -> wb[c*16+q][p] bf16
    #pragma unroll 4
    for (int u = 0; u < 32; ++u) {
        int idx = u * 256 + tid;               // c*256 + p*16 + q
        int c = idx >> 8, p = (idx >> 4) & 15, q = idx & 15;
        wb[(c * 16 + q) * 40 + p] = f2bf(w[(size_t)i2 * 8192 + idx]);
    }
    // fused gather: pb[nn][p] from x via reference reshape scramble
    #pragma unroll
    for (int u = 0; u < 8; ++u) {
        int idx = u * 256 + tid;               // nn*16 + p
        int nn = idx >> 4, p = idx & 15;
        int e  = i2 * 16 + p;
        int k2 = e >> 9, c2 = e & 511;
        int f  = k2 * 544 + c2;
        int ci = f / 9, kk = f - ci * 9;
        int bi = nn >> 6, oi = (nn >> 3) & 7, oj = nn & 7;
        int row = 2 * oi + kk / 3 - 1;
        int col = 2 * oj + (kk - (kk / 3) * 3) - 1;
        float val = 0.f;
        if ((unsigned)row < 16u && (unsigned)col < 16u)
            val = x[((bi * 16 + row) * 16 + col) * 544 + ci];
        pb[nn * 40 + p] = f2bf(val);
    }
    __syncthreads();

    const int lane = tid & 63;
    const int wv   = tid >> 6;
    const int l16  = lane & 15;
    const int quad = lane >> 4;
    const int cq0  = wv * 128;

    s8v afrag[8], bfrag[8];
    #pragma unroll
    for (int mt = 0; mt < 8; ++mt)
        afrag[mt] = *(const s8v*)&wb[(cq0 + mt * 16 + l16) * 40 + quad * 8];
    #pragma unroll
    for (int nt = 0; nt < 8; ++nt)
        bfrag[nt] = *(const s8v*)&pb[(nt * 16 + l16) * 40 + quad * 8];

    #pragma unroll
    for (int nt = 0; nt < 8; ++nt) {
        const int nl = nt * 16 + l16;
        #pragma unroll
        for (int mt = 0; mt < 8; ++mt) {
            f4v acc = {0.f, 0.f, 0.f, 0.f};
            acc = __builtin_amdgcn_mfma_f32_16x16x32_bf16(afrag[mt], bfrag[nt], acc, 0, 0, 0);
            int cq = cq0 + mt * 16 + quad * 4;
            unsigned int lo = f2bf(acc[0]) | ((unsigned int)f2bf(acc[1]) << 16);
            unsigned int hi = f2bf(acc[2]) | ((unsigned int)f2bf(acc[3]) << 16);
            uint2 pk; pk.x = lo; pk.y = hi;
            *(uint2*)((unsigned short*)vout + ((size_t)nl * 288 + i2) * 512 + cq) = pk;
        }
    }
}

// Kernel 2: EM routing, fused single sweep, q split across wave halves,
// 2-row ILP + next-pair prefetch (software pipeline to raise outstanding
// loads per wave). Block = 1024 = 16 waves; wave wv owns rows {16k+wv}.
__global__ __launch_bounds__(1024, 4)
void em_routing_kernel(const float* __restrict__ x,
                       const unsigned short* __restrict__ v,   // [n][i][cq] bf16
                       const float* __restrict__ beta_u,
                       const float* __restrict__ beta_a,
                       float* __restrict__ out)
{
    __shared__ float fct_s[288];            // a/(a+eps)
    __shared__ float red_s[16 * 64 * 17];   // [wave][lane][s0|s1[8]|s2[8]]
    __shared__ float mu_s[32 * 17];
    __shared__ float i2ss_s[32 * 17];
    __shared__ float hlog_s[32 * 17];
    __shared__ float rsum_s[32];
    __shared__ float aout_s[32];
    __shared__ float kc_s[32];

    const int n   = blockIdx.x;
    const int tid = threadIdx.x;
    const int bi = n >> 6, oi = (n >> 3) & 7, oj = n & 7;

    if (tid < 288) {
        // a_in gather: c2 in [512,544)
        int k2 = tid >> 5;
        int c2 = 512 + (tid & 31);
        int f  = k2 * 544 + c2;
        int ci = f / 9;
        int kk = f - ci * 9;
        int row = 2 * oi + kk / 3 - 1;
        int col = 2 * oj + (kk - (kk / 3) * 3) - 1;
        float a = 0.f;
        if ((unsigned)row < 16u && (unsigned)col < 16u)
            a = x[((bi * 16 + row) * 16 + col) * 544 + ci];
        fct_s[tid] = a / (a + EPSV);   // sum_c r*a == a -> rr = softmax * fct
    }
    __syncthreads();

    const unsigned short* vb = v + (size_t)n * 288 * 512;
    const int wv   = tid >> 6;      // wave 0..15
    const int lane = tid & 63;
    const int c    = lane & 31;
    const int qh   = lane >> 5;     // q-half 0/1
    const int qb   = qh * 8;
    const unsigned short* base = vb + c * 16 + qb;

    for (int t = 0; t < 3; ++t) {
        float mu8[8], is8[8], kcv = 0.f;
        if (t > 0) {
            #pragma unroll
            for (int j = 0; j < 8; ++j) {
                mu8[j] = mu_s[c * 17 + qb + j];
                is8[j] = i2ss_s[c * 17 + qb + j];
            }
            kcv = kc_s[c];
        }

        float s0 = 0.f, s1[8], s2[8];
        #pragma unroll
        for (int j = 0; j < 8; ++j) { s1[j] = 0.f; s2[j] = 0.f; }

        // prefetch pair 0
        uint4 ua = *(const uint4*)(base + (size_t)(0 * 16 + wv) * 512);
        uint4 ub = *(const uint4*)(base + (size_t)(1 * 16 + wv) * 512);

        for (int kp = 0; kp < 9; ++kp) {
            const int ia = (2 * kp) * 16 + wv;
            const int ib = (2 * kp + 1) * 16 + wv;
            uint4 una, unb;
            if (kp < 8) {   // issue next pair before the compute chain
                una = *(const uint4*)(base + (size_t)((2 * kp + 2) * 16 + wv) * 512);
                unb = *(const uint4*)(base + (size_t)((2 * kp + 3) * 16 + wv) * 512);
            }
            float va[8], vvb[8];
            va[0] = bflo(ua.x); va[1] = bfhi(ua.x);
            va[2] = bflo(ua.y); va[3] = bfhi(ua.y);
            va[4] = bflo(ua.z); va[5] = bfhi(ua.z);
            va[6] = bflo(ua.w); va[7] = bfhi(ua.w);
            vvb[0] = bflo(ub.x); vvb[1] = bfhi(ub.x);
            vvb[2] = bflo(ub.y); vvb[3] = bfhi(ub.y);
            vvb[4] = bflo(ub.z); vvb[5] = bfhi(ub.z);
            vvb[6] = bflo(ub.w); vvb[7] = bfhi(ub.w);

            float rra, rrb;
            if (t == 0) {
                rra = fct_s[ia] * 0.03125f;
                rrb = fct_s[ib] * 0.03125f;
            } else {
                float pa = 0.f, pb2 = 0.f;
                #pragma unroll
                for (int j = 0; j < 8; ++j) {
                    float da = va[j] - mu8[j];
                    float db = vvb[j] - mu8[j];
                    pa  += da * da * is8[j];
                    pb2 += db * db * is8[j];
                }
                pa  += __shfl_xor(pa, 32, 64);
                pb2 += __shfl_xor(pb2, 32, 64);
                float acca = kcv - pa;
                float accb = kcv - pb2;
                float mxa = acca, mxb = accb;
                mxa = fmaxf(mxa, __shfl_xor(mxa, 1, 32));  mxb = fmaxf(mxb, __shfl_xor(mxb, 1, 32));
                mxa = fmaxf(mxa, __shfl_xor(mxa, 2, 32));  mxb = fmaxf(mxb, __shfl_xor(mxb, 2, 32));
                mxa = fmaxf(mxa, __shfl_xor(mxa, 4, 32));  mxb = fmaxf(mxb, __shfl_xor(mxb, 4, 32));
                mxa = fmaxf(mxa, __shfl_xor(mxa, 8, 32));  mxb = fmaxf(mxb, __shfl_xor(mxb, 8, 32));
                mxa = fmaxf(mxa, __shfl_xor(mxa, 16, 32)); mxb = fmaxf(mxb, __shfl_xor(mxb, 16, 32));
                float ea = __expf(acca - mxa);
                float eb = __expf(accb - mxb);
                float sa = ea, sb = eb;
                sa += __shfl_xor(sa, 1, 32);  sb += __shfl_xor(sb, 1, 32);
                sa += __shfl_xor(sa, 2, 32);  sb += __shfl_xor(sb, 2, 32);
                sa += __shfl_xor(sa, 4, 32);  sb += __shfl_xor(sb, 4, 32);
                sa += __shfl_xor(sa, 8, 32);  sb += __shfl_xor(sb, 8, 32);
                sa += __shfl_xor(sa, 16, 32); sb += __shfl_xor(sb, 16, 32);
                rra = (ea / sa) * fct_s[ia];
                rrb = (eb / sb) * fct_s[ib];
            }

            s0 += rra + rrb;
            #pragma unroll
            for (int j = 0; j < 8; ++j) {
                s1[j] += rra * va[j] + rrb * vvb[j];
                s2[j] += rra * va[j] * va[j] + rrb * vvb[j] * vvb[j];
            }
            ua = una; ub = unb;
        }

        // per-wave partials -> LDS (stride 17: 2-way bank alias = free)
        {
            float* dst = &red_s[(wv * 64 + lane) * 17];
            dst[0] = s0;
            #pragma unroll
            for (int j = 0; j < 8; ++j) { dst[1 + j] = s1[j]; dst[9 + j] = s2[j]; }
        }
        __syncthreads();

        // final 16-way reduce + mu/sigma (thread = (c2,q2))
        if (tid < 512) {
            int c2 = tid >> 4, q2 = tid & 15;
            int qh2 = q2 >> 3, j2 = q2 & 7;
            float S0 = 0.f, S1 = 0.f, S2 = 0.f;
            #pragma unroll
            for (int wvi = 0; wvi < 16; ++wvi) {
                S0 += red_s[(wvi * 64 + c2) * 17];
                const float* sp = &red_s[(wvi * 64 + qh2 * 32 + c2) * 17];
                S1 += sp[1 + j2];
                S2 += sp[9 + j2];
            }
            if (q2 == 0) rsum_s[c2] = S0;
            float invr = 1.0f / (S0 + EPSV);
            float w0  = S0 * invr;
            float m   = S1 * invr;
            float s2p = S2 * invr;
            float sig = s2p - m * m * (2.0f - w0);   // == sum coeff*(v-mu)^2
            sig = fmaxf(sig + EPSV, 1e-4f);
            float hl = 0.5f * logf(sig);
            mu_s[c2 * 17 + q2]   = m;
            hlog_s[c2 * 17 + q2] = hl;
            i2ss_s[c2 * 17 + q2] = 1.0f / (2.0f * sig);
        }
        __syncthreads();

        // a_out + per-c ln_p constant
        if (tid < 32) {
            float cs = 0.f, shl = 0.f;
            float bu = beta_u[tid];
            #pragma unroll
            for (int q = 0; q < 16; ++q) { float hl = hlog_s[tid * 17 + q]; shl += hl; cs += bu + hl; }
            cs *= rsum_s[tid];
            float arg = LAMBDAV * (beta_a[tid] - cs);
            float ao  = 1.0f / (1.0f + expf(-arg));
            ao = fminf(fmaxf(ao, 1e-4f), 1.0f - 1e-4f);
            aout_s[tid] = ao;
            kc_s[tid]   = logf(ao + EPSV) - shl - 8.0f * LN_2PI;
        }
        __syncthreads();
    }

    // epilogue (fp32): p_out [0,65536) | a_out [65536,69632) | out [69632,139264)
    if (tid < 512) {
        int c2 = tid >> 4, q2 = tid & 15;
        float mu = mu_s[c2 * 17 + q2];
        if (isnan(mu)) mu = 0.f;
        mu = fminf(fmaxf(mu, -10000.f), 10000.f);
        out[(size_t)n * 512 + tid] = mu;
        out[69632 + (size_t)n * 544 + tid] = mu;
        if (tid < 32) {
            float ao = aout_s[tid];
            if (isnan(ao)) ao = 0.5f;
            out[65536 + n * 32 + tid] = ao;
            out[69632 + n * 544 + 512 + tid] = ao;
        }
    }
}

extern "C" void kernel_launch(void* const* d_in, const int* in_sizes, int n_in,
                              void* d_out, int out_size, void* d_ws, size_t ws_size,
                              hipStream_t stream) {
    const float* x  = (const float*)d_in[0];
    const float* w  = (const float*)d_in[1];
    const float* bu = (const float*)d_in[2];
    const float* ba = (const float*)d_in[3];
    float* out = (float*)d_out;
    __hip_bfloat16* v = (__hip_bfloat16*)d_ws;  // 128*288*512 bf16 = 37.7 MB
    // ws_size >= 75 MB (proven by R4's fp32-v run at CN=128): no chunking.

    conv_v_kernel<<<dim3(288), dim3(256), 0, stream>>>(x, w, v);
    em_routing_kernel<<<dim3(128), dim3(1024), 0, stream>>>(
        x, (const unsigned short*)v, bu, ba, out);
}